// Round 1
// 579.712 us; speedup vs baseline: 1.1992x; 1.1992x over previous
//
#include <hip/hip_runtime.h>

#define NN 50000
#define NE 800000
#define PD 128
#define NBLK 196       // ceil(NN/256)
#define GB1 391        // ceil(25000/64) blocks for input1
#define M_HALF 25000

typedef __attribute__((ext_vector_type(8))) short bf16x8;
typedef __attribute__((ext_vector_type(4))) float f32x4;

__device__ __forceinline__ float bf2f(unsigned short h) {
  union { unsigned u; float f; } v; v.u = ((unsigned)h) << 16; return v.f;
}
__device__ __forceinline__ unsigned short f2bf(float f) {
  union { float f; unsigned u; } v; v.f = f;
  unsigned r = (v.u + 0x7FFFu + ((v.u >> 16) & 1u)) >> 16;
  return (unsigned short)r;
}
__device__ __forceinline__ unsigned pack2(float a, float b) {
  return (unsigned)f2bf(a) | ((unsigned)f2bf(b) << 16);
}

// ---------------------------------------------------------------------------
// Composite weights, CHUNK-MAJOR + PRE-SWIZZLED for global_load_lds:
// logical Wc[n][k] = bf16( sum_p Wp[k][p]*WLR[p][n] ), n in [0,256).
// Storage: chunk ch = k>>5 is a contiguous 16 KB block of 1024 16B granules;
// element (n, k) lives at granule g = n*4 + (kq ^ ((n>>1)&3)), kq=(k>>3)&3,
// byte e = k&7 within granule. Linear DMA of a chunk then lands an
// XOR-swizzled (bank-conflict-free) LDS image.
// biasc[0..255] = bp1 @ WLR ; biasc[256..511] = bp2 @ WLR.
__global__ __launch_bounds__(256) void wtrans(
    const float* __restrict__ Wp1, const float* __restrict__ Wp2,
    const float* __restrict__ Wl, const float* __restrict__ Wr,
    const float* __restrict__ bp1, const float* __restrict__ bp2,
    unsigned short* __restrict__ Wct1, unsigned short* __restrict__ Wct2,
    float* __restrict__ biasc) {
  int b = blockIdx.x, n = threadIdx.x;
  __shared__ float arow[128];
  const float* W = (n < 128) ? Wl : Wr;
  int nc = n & 127;
  if (b < 2560) {
    int is1 = (b < 2048) ? 1 : 0;
    int k = is1 ? b : (b - 2048);
    int Kv = is1 ? 2000 : 500;
    unsigned short v = 0;
    if (k < Kv) {
      if (n < 128) arow[n] = is1 ? Wp1[k * 128 + n] : Wp2[k * 128 + n];
      __syncthreads();
      float s = 0.f;
      for (int p = 0; p < 128; ++p) s += arow[p] * W[p * 128 + nc];
      v = f2bf(s);
    }
    int ch = k >> 5, kq = (k >> 3) & 3, e = k & 7;
    size_t idx = (size_t)ch * 8192 + (size_t)(n * 4 + (kq ^ ((n >> 1) & 3))) * 8 + e;
    if (is1) Wct1[idx] = v; else Wct2[idx] = v;
  } else {
    float s1 = 0.f, s2 = 0.f;
    for (int p = 0; p < 128; ++p) {
      float w = W[p * 128 + nc];
      s1 += bp1[p] * w;
      s2 += bp2[p] * w;
    }
    biasc[n] = s1;
    biasc[256 + n] = s2;
  }
}

// ---------------------------------------------------------------------------
// Fused GEMM, m97-style: tile 64(M) x 256(N), K-chunk 32, double-buffered.
// Wave tile 64x64 (wave w -> cols w*64..+63): 4 A-frags + 4 B-frags per chunk
// for 16 MFMAs (vs 17 reads/16 MFMA before). B staged by global_load_lds
// width=16 from the pre-swizzled chunk-major Wct (no VGPR round-trip);
// A reg-staged with fp32->bf16 pack into padded stride-40 LDS.
__global__ __launch_bounds__(256) void big_gemm(
    const float* __restrict__ x1, const float* __restrict__ x2,
    const unsigned short* __restrict__ Wct1, const unsigned short* __restrict__ Wct2,
    const float* __restrict__ biasc,
    unsigned short* __restrict__ XLb, float* __restrict__ XR) {
  // per buffer: As 64x40 u16 (5120 B) + Bs 256x32 u16 (16384 B) = 21504 B; x2
  __shared__ __align__(64) unsigned short lds[2 * 10752];
  int tid = threadIdx.x;
  int wave = tid >> 6, lane = tid & 63;
  int m16 = lane & 15, quad = lane >> 4;

  int inp = (blockIdx.x >= GB1) ? 1 : 0;
  int blk = inp ? (blockIdx.x - GB1) : blockIdx.x;
  const float* A = inp ? x2 : x1;
  const unsigned short* Wct = inp ? Wct2 : Wct1;
  const int K = inp ? 500 : 2000;
  const int nch = inp ? 16 : 63;
  int row0 = blk * 64;

  // A staging: thread t stages row ar = t>>2, k-octet ako = (t&3)*8
  int ar = tid >> 2, ako = (tid & 3) << 3;
  bool arow_ok = (row0 + ar) < M_HALF;
  const float* aptr = A + (size_t)(row0 + ar) * K + ako;

  // fragment LDS offsets (u16 units)
  int swz = (quad ^ ((m16 >> 1) & 3)) << 3;   // B granule XOR-swizzle
  int boffA[4], boffB[4];
#pragma unroll
  for (int i = 0; i < 4; ++i) boffA[i] = (i * 16 + m16) * 40 + quad * 8;
#pragma unroll
  for (int j = 0; j < 4; ++j) boffB[j] = (wave * 64 + j * 16 + m16) * 32 + swz;

  f32x4 acc[4][4];
#pragma unroll
  for (int i = 0; i < 4; ++i)
#pragma unroll
    for (int j = 0; j < 4; ++j) acc[i][j] = (f32x4){0.f, 0.f, 0.f, 0.f};

  float4 pa0, pa1;

#define GLB(ch, buf)                                                          \
  {                                                                           \
    const unsigned short* wp_ = Wct + (size_t)(ch) * 8192;                    \
    unsigned short* bb_ = lds + (buf) * 10752 + 2560;                         \
    _Pragma("unroll") for (int ii = 0; ii < 4; ++ii) {                        \
      int gb_ = (ii * 4 + wave) * 64;                                         \
      __builtin_amdgcn_global_load_lds(                                       \
          (const __attribute__((address_space(1))) void*)(wp_ +               \
              (size_t)(gb_ + lane) * 8),                                      \
          (__attribute__((address_space(3))) void*)(bb_ + (size_t)gb_ * 8),   \
          16, 0, 0);                                                          \
    }                                                                         \
  }

#define LOADA(ch)                                                             \
  {                                                                           \
    int k0_ = (ch) * 32;                                                      \
    if (arow_ok) {                                                            \
      pa0 = *(const float4*)(aptr + k0_);                                     \
      pa1 = *(const float4*)(aptr + k0_ + 4);                                 \
    }                                                                         \
  }

#define STOREA(buf)                                                           \
  {                                                                           \
    unsigned short* As_ = lds + (buf) * 10752;                                \
    uint4 wA;                                                                 \
    if (arow_ok) {                                                            \
      wA.x = pack2(pa0.x, pa0.y); wA.y = pack2(pa0.z, pa0.w);                 \
      wA.z = pack2(pa1.x, pa1.y); wA.w = pack2(pa1.z, pa1.w);                 \
    } else { wA.x = wA.y = wA.z = wA.w = 0u; }                                \
    *(uint4*)(As_ + ar * 40 + ako) = wA;                                      \
  }

  GLB(0, 0);
  LOADA(0);
  STOREA(0);
  __syncthreads();

  for (int ch = 0; ch < nch; ++ch) {
    int cur = ch & 1;
    if (ch + 1 < nch) { GLB(ch + 1, cur ^ 1); LOADA(ch + 1); }
    {
      const unsigned short* As_ = lds + cur * 10752;
      const unsigned short* Bs_ = As_ + 2560;
      bf16x8 a[4], b[4];
#pragma unroll
      for (int i = 0; i < 4; ++i) a[i] = *(const bf16x8*)(As_ + boffA[i]);
#pragma unroll
      for (int j = 0; j < 4; ++j) b[j] = *(const bf16x8*)(Bs_ + boffB[j]);
#pragma unroll
      for (int i = 0; i < 4; ++i)
#pragma unroll
        for (int j = 0; j < 4; ++j)
          acc[i][j] =
              __builtin_amdgcn_mfma_f32_16x16x32_bf16(a[i], b[j], acc[i][j], 0, 0, 0);
    }
    if (ch + 1 < nch) STOREA(cur ^ 1);
    __syncthreads();
  }

  // epilogue: C/D layout col=lane&15, row=quad*4+r within each 16x16 tile
  const float* bc = biasc + inp * 256;
#pragma unroll
  for (int i = 0; i < 4; ++i) {
    int rb = row0 + i * 16 + quad * 4;
#pragma unroll
    for (int j = 0; j < 4; ++j) {
      int c = wave * 64 + j * 16 + m16;
      float bv = bc[c];
#pragma unroll
      for (int r = 0; r < 4; ++r) {
        if (rb + r < M_HALF) {
          size_t grow = (size_t)inp * M_HALF + rb + r;
          float v = acc[i][j][r] + bv;
          if (c < PD) XLb[grow * PD + c] = f2bf(v);
          else XR[grow * PD + (c - PD)] = v;
        }
      }
    }
  }
#undef GLB
#undef LOADA
#undef STOREA
}

// ---------------------------------------------------------------------------
// CSR build: histogram -> 2-level exclusive scan -> scatter
__global__ __launch_bounds__(256) void zero_deg(int* __restrict__ deg) {
  int i = blockIdx.x * 256 + threadIdx.x;
  if (i < NN) deg[i] = 0;
}

__global__ __launch_bounds__(256) void hist(const int* __restrict__ edge,
                                            int* __restrict__ deg) {
  int i = blockIdx.x * 256 + threadIdx.x;
  if (i < NE) atomicAdd(&deg[edge[NE + i]], 1);
}

__global__ __launch_bounds__(256) void scan1(const int* __restrict__ deg,
                                             int* __restrict__ bsum) {
  __shared__ int sd[256];
  int i = blockIdx.x * 256 + threadIdx.x;
  sd[threadIdx.x] = (i < NN) ? deg[i] : 0;
  __syncthreads();
  for (int off = 128; off > 0; off >>= 1) {
    if (threadIdx.x < off) sd[threadIdx.x] += sd[threadIdx.x + off];
    __syncthreads();
  }
  if (threadIdx.x == 0) bsum[blockIdx.x] = sd[0];
}

__global__ __launch_bounds__(64) void scan2(const int* __restrict__ bsum,
                                            int* __restrict__ boff) {
  if (threadIdx.x == 0) {
    int run = 0;
    for (int b = 0; b < NBLK; ++b) { boff[b] = run; run += bsum[b]; }
  }
}

__global__ __launch_bounds__(256) void scan3(const int* __restrict__ deg,
                                             const int* __restrict__ boff,
                                             int* __restrict__ start,
                                             int* __restrict__ cursor) {
  __shared__ int sd[256];
  int i = blockIdx.x * 256 + threadIdx.x;
  int v = (i < NN) ? deg[i] : 0;
  sd[threadIdx.x] = v;
  __syncthreads();
  for (int off = 1; off < 256; off <<= 1) {
    int t = (threadIdx.x >= off) ? sd[threadIdx.x - off] : 0;
    __syncthreads();
    sd[threadIdx.x] += t;
    __syncthreads();
  }
  if (i < NN) {
    int excl = boff[blockIdx.x] + sd[threadIdx.x] - v;
    start[i] = excl;
    cursor[i] = excl;
  }
  if (blockIdx.x == 0 && threadIdx.x == 0) start[NN] = NE;
}

__global__ __launch_bounds__(256) void scatter(const int* __restrict__ edge,
                                               int* __restrict__ cursor,
                                               int* __restrict__ esrc) {
  int i = blockIdx.x * 256 + threadIdx.x;
  if (i < NE) {
    int dst = edge[NE + i];
    int pos = atomicAdd(&cursor[dst], 1);
    esrc[pos] = edge[i];
  }
}

// ---------------------------------------------------------------------------
// Fused GATv2: one wave per dst node, online softmax, no atomics.
// Lane l: head h = l>>4; features f0 = 2l, 2l+1.
__global__ __launch_bounds__(256) void gat_fused(
    const unsigned short* __restrict__ XLb, const float* __restrict__ XR,
    const float* __restrict__ att, const float* __restrict__ bg,
    const int* __restrict__ start, const int* __restrict__ esrc,
    float* __restrict__ out) {
  int wave = threadIdx.x >> 6, lane = threadIdx.x & 63;
  int d = blockIdx.x * 4 + wave;
  int f0 = lane * 2;

  float2 xr = *(const float2*)(XR + (size_t)d * PD + f0);
  float a0c = att[f0], a1c = att[f0 + 1];

  int s = start[d], e_end = start[d + 1];

  float m = -INFINITY, l = 0.f, acc0 = 0.f, acc1 = 0.f;
  for (int j = s; j < e_end; ++j) {
    int src = esrc[j];
    unsigned xlu = *(const unsigned*)(XLb + (size_t)src * PD + f0);
    float xl0 = bf2f((unsigned short)(xlu & 0xFFFFu));
    float xl1 = bf2f((unsigned short)(xlu >> 16));
    float z0 = xl0 + xr.x, z1 = xl1 + xr.y;
    float g0 = z0 > 0.f ? z0 : 0.2f * z0;
    float g1 = z1 > 0.f ? z1 : 0.2f * z1;
    float t = a0c * g0 + a1c * g1;
    t += __shfl_xor(t, 1);
    t += __shfl_xor(t, 2);
    t += __shfl_xor(t, 4);
    t += __shfl_xor(t, 8);
    float mn = fmaxf(m, t);
    float c = __expf(m - mn);
    float p = __expf(t - mn);
    l = l * c + p;
    acc0 = acc0 * c + p * xl0;
    acc1 = acc1 * c + p * xl1;
    m = mn;
  }

  float inv = 1.f / (l + 1e-16f);
  float v0 = acc0 * inv + bg[f0];
  float v1 = acc1 * inv + bg[f0 + 1];
  v0 = v0 > 0.f ? v0 : expm1f(v0);
  v1 = v1 > 0.f ? v1 : expm1f(v1);
  *(float2*)(out + (size_t)d * PD + f0) = make_float2(v0, v1);
}

// ---------------------------------------------------------------------------
extern "C" void kernel_launch(void* const* d_in, const int* in_sizes, int n_in,
                              void* d_out, int out_size, void* d_ws, size_t ws_size,
                              hipStream_t stream) {
  const float* x1  = (const float*)d_in[0];
  const float* x2  = (const float*)d_in[1];
  const float* Wp1 = (const float*)d_in[2];
  const float* bp1 = (const float*)d_in[3];
  const float* Wp2 = (const float*)d_in[4];
  const float* bp2 = (const float*)d_in[5];
  const float* Wl  = (const float*)d_in[6];
  const float* Wr  = (const float*)d_in[7];
  const float* att = (const float*)d_in[8];
  const float* bg  = (const float*)d_in[9];
  const int*   edge = (const int*)d_in[10];

  // workspace (~43.5 MB)
  char* ws = (char*)d_ws;
  unsigned short* XLb   = (unsigned short*)(ws);               // 12.8 MB
  float*          XR    = (float*)(ws + 12800000);             // 25.6 MB
  int*            esrc  = (int*)(ws + 38400000);               // 3.2 MB
  int*            start = (int*)(ws + 41600000);               // (NN+1)*4
  int*            cursor = (int*)(ws + 41800192);
  int*            deg   = (int*)(ws + 42000384);
  int*            bsum  = (int*)(ws + 42200576);
  int*            boff  = (int*)(ws + 42201600);
  unsigned short* Wct1  = (unsigned short*)(ws + 42202624);    // 1 MB, 64 chunks
  unsigned short* Wct2  = (unsigned short*)(ws + 43251200);    // 256 KB, 16 chunks
  float*          biasc = (float*)(ws + 43513344);             // [2][256]

  // composite weights (independent, tiny)
  wtrans<<<2561, 256, 0, stream>>>(Wp1, Wp2, Wl, Wr, bp1, bp2, Wct1, Wct2, biasc);

  // CSR build
  zero_deg<<<NBLK, 256, 0, stream>>>(deg);
  hist<<<(NE + 255) / 256, 256, 0, stream>>>(edge, deg);
  scan1<<<NBLK, 256, 0, stream>>>(deg, bsum);
  scan2<<<1, 64, 0, stream>>>(bsum, boff);
  scan3<<<NBLK, 256, 0, stream>>>(deg, boff, start, cursor);
  scatter<<<(NE + 255) / 256, 256, 0, stream>>>(edge, cursor, esrc);

  // one fused GEMM producing XLb (bf16) and XR (fp32)
  big_gemm<<<GB1 * 2, 256, 0, stream>>>(x1, x2, Wct1, Wct2, biasc, XLb, XR);

  // fused attention + aggregation + ELU
  gat_fused<<<NN / 4, 256, 0, stream>>>(XLb, XR, att, bg, start, esrc,
                                        (float*)d_out);
}

// Round 2
// 531.046 us; speedup vs baseline: 1.3091x; 1.0916x over previous
//
#include <hip/hip_runtime.h>

#define NN 50000
#define NE 800000
#define PD 128
#define NBLK 196       // ceil(NN/256)
#define GB1 391        // ceil(25000/64) blocks for input1
#define M_HALF 25000

typedef __attribute__((ext_vector_type(8))) short bf16x8;
typedef __attribute__((ext_vector_type(4))) float f32x4;

__device__ __forceinline__ float bf2f(unsigned short h) {
  union { unsigned u; float f; } v; v.u = ((unsigned)h) << 16; return v.f;
}
__device__ __forceinline__ unsigned short f2bf(float f) {
  union { float f; unsigned u; } v; v.f = f;
  unsigned r = (v.u + 0x7FFFu + ((v.u >> 16) & 1u)) >> 16;
  return (unsigned short)r;
}
__device__ __forceinline__ unsigned pack2(float a, float b) {
  return (unsigned)f2bf(a) | ((unsigned)f2bf(b) << 16);
}

// ---------------------------------------------------------------------------
// Composite weights, CHUNK-MAJOR + PRE-SWIZZLED for global_load_lds:
// logical Wc[n][k] = bf16( sum_p Wp[k][p]*WLR[p][n] ), n in [0,256).
// chunk ch = k>>5 is a contiguous 16 KB block of 1024 16B granules;
// element (n,k) -> granule g = n*4 + (kq ^ ((n>>1)&3)), kq=(k>>3)&3, e=k&7.
// biasc[0..255] = bp1 @ WLR ; biasc[256..511] = bp2 @ WLR.
// Tail blocks (>=2561) zero the degree histogram (fused zero_deg).
__global__ __launch_bounds__(256) void wtrans(
    const float* __restrict__ Wp1, const float* __restrict__ Wp2,
    const float* __restrict__ Wl, const float* __restrict__ Wr,
    const float* __restrict__ bp1, const float* __restrict__ bp2,
    unsigned short* __restrict__ Wct1, unsigned short* __restrict__ Wct2,
    float* __restrict__ biasc, int* __restrict__ deg) {
  int b = blockIdx.x, n = threadIdx.x;
  __shared__ float arow[128];
  if (b > 2560) {
    int i = (b - 2561) * 256 + n;
    if (i < NN) deg[i] = 0;
    return;
  }
  const float* W = (n < 128) ? Wl : Wr;
  int nc = n & 127;
  if (b < 2560) {
    int is1 = (b < 2048) ? 1 : 0;
    int k = is1 ? b : (b - 2048);
    int Kv = is1 ? 2000 : 500;
    unsigned short v = 0;
    if (k < Kv) {
      if (n < 128) arow[n] = is1 ? Wp1[k * 128 + n] : Wp2[k * 128 + n];
      __syncthreads();
      float s = 0.f;
      for (int p = 0; p < 128; ++p) s += arow[p] * W[p * 128 + nc];
      v = f2bf(s);
    }
    int ch = k >> 5, kq = (k >> 3) & 3, e = k & 7;
    size_t idx = (size_t)ch * 8192 + (size_t)(n * 4 + (kq ^ ((n >> 1) & 3))) * 8 + e;
    if (is1) Wct1[idx] = v; else Wct2[idx] = v;
  } else {
    float s1 = 0.f, s2 = 0.f;
    for (int p = 0; p < 128; ++p) {
      float w = W[p * 128 + nc];
      s1 += bp1[p] * w;
      s2 += bp2[p] * w;
    }
    biasc[n] = s1;
    biasc[256 + n] = s2;
  }
}

// ---------------------------------------------------------------------------
// Fused GEMM: tile 64(M) x 256(N), K-chunk 32, double-buffered, T3/T4-style
// counted-vmcnt pipeline: raw s_barrier, no vmcnt drain in the main loop.
// Wave w DMAs exactly the B granules it later reads (self-assigned), so a
// per-wave s_waitcnt vmcnt(6) proves its own B tile landed. A is reg-staged
// (fp32->bf16), loads issued one full iteration before consumption.
__global__ __launch_bounds__(256) void big_gemm(
    const float* __restrict__ x1, const float* __restrict__ x2,
    const unsigned short* __restrict__ Wct1, const unsigned short* __restrict__ Wct2,
    const float* __restrict__ biasc,
    unsigned short* __restrict__ XLb, float* __restrict__ XR) {
  // per buffer: As 64x40 u16 (5120 B) + Bs 256x32 u16 (16384 B) = 21504 B; x2
  __shared__ __align__(64) unsigned short lds[2 * 10752];
  int tid = threadIdx.x;
  int wave = tid >> 6, lane = tid & 63;
  int m16 = lane & 15, quad = lane >> 4;

  int inp = (blockIdx.x >= GB1) ? 1 : 0;
  int blk = inp ? (blockIdx.x - GB1) : blockIdx.x;
  const float* A = inp ? x2 : x1;
  const unsigned short* Wct = inp ? Wct2 : Wct1;
  const int K = inp ? 500 : 2000;
  const int nch = inp ? 16 : 63;
  int row0 = blk * 64;

  // A staging: thread t stages row ar = t>>2, k-octet ako = (t&3)*8.
  // Unconditional loads (clamped row) so every thread issues identical VMEM
  // counts per iteration -- required for the counted vmcnt to be exact.
  int ar = tid >> 2, ako = (tid & 3) << 3;
  int arc = row0 + ar;
  bool arow_ok = arc < M_HALF;
  const float* aptr = A + (size_t)(arow_ok ? arc : 0) * K + ako;

  // fragment LDS offsets (u16 units)
  int swz = (quad ^ ((m16 >> 1) & 3)) << 3;   // B granule XOR-swizzle
  int boffA[4], boffB[4];
#pragma unroll
  for (int i = 0; i < 4; ++i) boffA[i] = (i * 16 + m16) * 40 + quad * 8;
#pragma unroll
  for (int j = 0; j < 4; ++j) boffB[j] = (wave * 64 + j * 16 + m16) * 32 + swz;

  f32x4 acc[4][4];
#pragma unroll
  for (int i = 0; i < 4; ++i)
#pragma unroll
    for (int j = 0; j < 4; ++j) acc[i][j] = (f32x4){0.f, 0.f, 0.f, 0.f};

  float4 pa0, pa1;

// wave-self-assigned B DMA: wave w writes granules [256w, 256w+256) = the
// n-rows [64w, 64w+64) it reads back as its B fragments.
#define GLB(ch, buf)                                                          \
  {                                                                           \
    const unsigned short* wp_ = Wct + (size_t)(ch) * 8192;                    \
    unsigned short* bb_ = lds + (buf) * 10752 + 2560;                         \
    _Pragma("unroll") for (int ii = 0; ii < 4; ++ii) {                        \
      int gb_ = wave * 256 + ii * 64;                                         \
      __builtin_amdgcn_global_load_lds(                                       \
          (const __attribute__((address_space(1))) void*)(wp_ +               \
              (size_t)(gb_ + lane) * 8),                                      \
          (__attribute__((address_space(3))) void*)(bb_ + (size_t)gb_ * 8),   \
          16, 0, 0);                                                          \
    }                                                                         \
  }

#define LOADA(ch)                                                             \
  {                                                                           \
    int k0_ = (ch) * 32;                                                      \
    pa0 = *(const float4*)(aptr + k0_);                                       \
    pa1 = *(const float4*)(aptr + k0_ + 4);                                   \
  }

#define STOREA(buf)                                                           \
  {                                                                           \
    unsigned short* As_ = lds + (buf) * 10752;                                \
    uint4 wA;                                                                 \
    if (arow_ok) {                                                            \
      wA.x = pack2(pa0.x, pa0.y); wA.y = pack2(pa0.z, pa0.w);                 \
      wA.z = pack2(pa1.x, pa1.y); wA.w = pack2(pa1.z, pa1.w);                 \
    } else { wA.x = wA.y = wA.z = wA.w = 0u; }                                \
    *(uint4*)(As_ + ar * 40 + ako) = wA;                                      \
  }

  // prologue: stage chunk 0, then pre-issue A for chunk 1
  LOADA(0);
  GLB(0, 0);
  STOREA(0);          // compiler inserts the vmcnt wait for pa regs
  LOADA(1);           // nch >= 16 always, so chunk 1 exists

  for (int ch = 0; ch < nch; ++ch) {
    int cur = ch & 1;
    // my ds_writes (STOREA) must be LDS-visible before anyone reads them
    asm volatile("s_waitcnt lgkmcnt(0)" ::: "memory");
    __builtin_amdgcn_s_barrier();
    __builtin_amdgcn_sched_barrier(0);
    if (ch + 1 < nch) {
      GLB(ch + 1, cur ^ 1);   // into the buffer everyone finished reading
      __builtin_amdgcn_sched_barrier(0);
      // own GLB(ch) done: newer in flight = LOADA(ch+1)[2] + GLB(ch+1)[4]
      asm volatile("s_waitcnt vmcnt(6)" ::: "memory");
    } else {
      asm volatile("s_waitcnt vmcnt(0)" ::: "memory");
    }
    __builtin_amdgcn_sched_barrier(0);
    {
      const unsigned short* As_ = lds + cur * 10752;
      const unsigned short* Bs_ = As_ + 2560;
      bf16x8 a[4], b[4];
#pragma unroll
      for (int i = 0; i < 4; ++i) a[i] = *(const bf16x8*)(As_ + boffA[i]);
#pragma unroll
      for (int j = 0; j < 4; ++j) b[j] = *(const bf16x8*)(Bs_ + boffB[j]);
#pragma unroll
      for (int i = 0; i < 4; ++i)
#pragma unroll
        for (int j = 0; j < 4; ++j)
          acc[i][j] =
              __builtin_amdgcn_mfma_f32_16x16x32_bf16(a[i], b[j], acc[i][j], 0, 0, 0);
    }
    if (ch + 1 < nch) {
      STOREA(cur ^ 1);          // consumes pa (chunk ch+1)
      if (ch + 2 < nch) LOADA(ch + 2);   // refill pa one iteration early
    }
  }

  // epilogue: C/D layout col=lane&15, row=quad*4+r within each 16x16 tile
  const float* bc = biasc + inp * 256;
#pragma unroll
  for (int i = 0; i < 4; ++i) {
    int rb = row0 + i * 16 + quad * 4;
#pragma unroll
    for (int j = 0; j < 4; ++j) {
      int c = wave * 64 + j * 16 + m16;
      float bv = bc[c];
#pragma unroll
      for (int r = 0; r < 4; ++r) {
        if (rb + r < M_HALF) {
          size_t grow = (size_t)inp * M_HALF + rb + r;
          float v = acc[i][j][r] + bv;
          if (c < PD) XLb[grow * PD + c] = f2bf(v);
          else XR[grow * PD + (c - PD)] = v;
        }
      }
    }
  }
#undef GLB
#undef LOADA
#undef STOREA
}

// ---------------------------------------------------------------------------
// CSR build: histogram -> block sums -> fused (block-offset + local scan)
__global__ __launch_bounds__(256) void hist(const int* __restrict__ edge,
                                            int* __restrict__ deg) {
  int i = blockIdx.x * 256 + threadIdx.x;
  if (i < NE) atomicAdd(&deg[edge[NE + i]], 1);
}

__global__ __launch_bounds__(256) void scan1(const int* __restrict__ deg,
                                             int* __restrict__ bsum) {
  __shared__ int sd[256];
  int i = blockIdx.x * 256 + threadIdx.x;
  sd[threadIdx.x] = (i < NN) ? deg[i] : 0;
  __syncthreads();
  for (int off = 128; off > 0; off >>= 1) {
    if (threadIdx.x < off) sd[threadIdx.x] += sd[threadIdx.x + off];
    __syncthreads();
  }
  if (threadIdx.x == 0) bsum[blockIdx.x] = sd[0];
}

// scan3: each block reduces its own prefix of bsum (196 <= 256 values) and
// does the local exclusive scan -- removes the serial scan2 kernel entirely.
__global__ __launch_bounds__(256) void scan3(const int* __restrict__ deg,
                                             const int* __restrict__ bsum,
                                             int* __restrict__ start,
                                             int* __restrict__ cursor) {
  __shared__ int sd[256];
  __shared__ int sb[256];
  int t = threadIdx.x;
  int i = blockIdx.x * 256 + t;
  sb[t] = (t < blockIdx.x) ? bsum[t] : 0;   // blockIdx.x <= 195 < 256
  int v = (i < NN) ? deg[i] : 0;
  sd[t] = v;
  __syncthreads();
  for (int off = 128; off > 0; off >>= 1) {
    if (t < off) sb[t] += sb[t + off];
    __syncthreads();
  }
  for (int off = 1; off < 256; off <<= 1) {
    int x = (t >= off) ? sd[t - off] : 0;
    __syncthreads();
    sd[t] += x;
    __syncthreads();
  }
  if (i < NN) {
    int excl = sb[0] + sd[t] - v;
    start[i] = excl;
    cursor[i] = excl;
  }
  if (blockIdx.x == 0 && t == 0) start[NN] = NE;
}

__global__ __launch_bounds__(256) void scatter(const int* __restrict__ edge,
                                               int* __restrict__ cursor,
                                               int* __restrict__ esrc) {
  int i = blockIdx.x * 256 + threadIdx.x;
  if (i < NE) {
    int dst = edge[NE + i];
    int pos = atomicAdd(&cursor[dst], 1);
    esrc[pos] = edge[i];
  }
}

// ---------------------------------------------------------------------------
// Fused GATv2: one wave per dst node, online softmax, no atomics.
// Lane l: head h = l>>4; features f0 = 2l, 2l+1. Edge loop unrolled x4 with
// batched gathers so the XLb row-gather latency overlaps across edges.
__global__ __launch_bounds__(256) void gat_fused(
    const unsigned short* __restrict__ XLb, const float* __restrict__ XR,
    const float* __restrict__ att, const float* __restrict__ bg,
    const int* __restrict__ start, const int* __restrict__ esrc,
    float* __restrict__ out) {
  int wave = threadIdx.x >> 6, lane = threadIdx.x & 63;
  int d = blockIdx.x * 4 + wave;
  int f0 = lane * 2;

  float2 xr = *(const float2*)(XR + (size_t)d * PD + f0);
  float a0c = att[f0], a1c = att[f0 + 1];

  int s = start[d], e_end = start[d + 1];

  float m = -INFINITY, l = 0.f, acc0 = 0.f, acc1 = 0.f;

#define UPD(xlu)                                                              \
  {                                                                           \
    float xl0 = bf2f((unsigned short)((xlu) & 0xFFFFu));                      \
    float xl1 = bf2f((unsigned short)((xlu) >> 16));                          \
    float z0 = xl0 + xr.x, z1 = xl1 + xr.y;                                   \
    float g0 = z0 > 0.f ? z0 : 0.2f * z0;                                     \
    float g1 = z1 > 0.f ? z1 : 0.2f * z1;                                     \
    float t = a0c * g0 + a1c * g1;                                            \
    t += __shfl_xor(t, 1);                                                    \
    t += __shfl_xor(t, 2);                                                    \
    t += __shfl_xor(t, 4);                                                    \
    t += __shfl_xor(t, 8);                                                    \
    float mn = fmaxf(m, t);                                                   \
    float c = __expf(m - mn);                                                 \
    float p = __expf(t - mn);                                                 \
    l = l * c + p;                                                            \
    acc0 = acc0 * c + p * xl0;                                                \
    acc1 = acc1 * c + p * xl1;                                                \
    m = mn;                                                                   \
  }

  int j = s;
  for (; j + 4 <= e_end; j += 4) {
    int s0 = esrc[j], s1 = esrc[j + 1], s2 = esrc[j + 2], s3 = esrc[j + 3];
    unsigned u0 = *(const unsigned*)(XLb + (size_t)s0 * PD + f0);
    unsigned u1 = *(const unsigned*)(XLb + (size_t)s1 * PD + f0);
    unsigned u2 = *(const unsigned*)(XLb + (size_t)s2 * PD + f0);
    unsigned u3 = *(const unsigned*)(XLb + (size_t)s3 * PD + f0);
    UPD(u0); UPD(u1); UPD(u2); UPD(u3);
  }
  for (; j < e_end; ++j) {
    int s0 = esrc[j];
    unsigned u0 = *(const unsigned*)(XLb + (size_t)s0 * PD + f0);
    UPD(u0);
  }
#undef UPD

  float inv = 1.f / (l + 1e-16f);
  float v0 = acc0 * inv + bg[f0];
  float v1 = acc1 * inv + bg[f0 + 1];
  v0 = v0 > 0.f ? v0 : expm1f(v0);
  v1 = v1 > 0.f ? v1 : expm1f(v1);
  *(float2*)(out + (size_t)d * PD + f0) = make_float2(v0, v1);
}

// ---------------------------------------------------------------------------
extern "C" void kernel_launch(void* const* d_in, const int* in_sizes, int n_in,
                              void* d_out, int out_size, void* d_ws, size_t ws_size,
                              hipStream_t stream) {
  const float* x1  = (const float*)d_in[0];
  const float* x2  = (const float*)d_in[1];
  const float* Wp1 = (const float*)d_in[2];
  const float* bp1 = (const float*)d_in[3];
  const float* Wp2 = (const float*)d_in[4];
  const float* bp2 = (const float*)d_in[5];
  const float* Wl  = (const float*)d_in[6];
  const float* Wr  = (const float*)d_in[7];
  const float* att = (const float*)d_in[8];
  const float* bg  = (const float*)d_in[9];
  const int*   edge = (const int*)d_in[10];

  // workspace (~43.5 MB)
  char* ws = (char*)d_ws;
  unsigned short* XLb   = (unsigned short*)(ws);               // 12.8 MB
  float*          XR    = (float*)(ws + 12800000);             // 25.6 MB
  int*            esrc  = (int*)(ws + 38400000);               // 3.2 MB
  int*            start = (int*)(ws + 41600000);               // (NN+1)*4
  int*            cursor = (int*)(ws + 41800192);
  int*            deg   = (int*)(ws + 42000384);
  int*            bsum  = (int*)(ws + 42200576);
  unsigned short* Wct1  = (unsigned short*)(ws + 42202624);    // 1 MB, 64 chunks
  unsigned short* Wct2  = (unsigned short*)(ws + 43251200);    // 256 KB, 16 chunks
  float*          biasc = (float*)(ws + 43513344);             // [2][256]

  // composite weights + fused deg zeroing (blocks 2561..2756)
  wtrans<<<2757, 256, 0, stream>>>(Wp1, Wp2, Wl, Wr, bp1, bp2, Wct1, Wct2,
                                   biasc, deg);

  // CSR build
  hist<<<(NE + 255) / 256, 256, 0, stream>>>(edge, deg);
  scan1<<<NBLK, 256, 0, stream>>>(deg, bsum);
  scan3<<<NBLK, 256, 0, stream>>>(deg, bsum, start, cursor);
  scatter<<<(NE + 255) / 256, 256, 0, stream>>>(edge, cursor, esrc);

  // one fused GEMM producing XLb (bf16) and XR (fp32)
  big_gemm<<<GB1 * 2, 256, 0, stream>>>(x1, x2, Wct1, Wct2, biasc, XLb, XR);

  // fused attention + aggregation + ELU
  gat_fused<<<NN / 4, 256, 0, stream>>>(XLb, XR, att, bg, start, esrc,
                                        (float*)d_out);
}